// Round 7
// baseline (588.666 us; speedup 1.0000x reference)
//
#include <hip/hip_runtime.h>
#include <math.h>

// ---------------------------------------------------------------------------
// Sizes (fixed by the reference)
// ---------------------------------------------------------------------------
#define N_NODES 2048
#define N_EDGES 4096
#define L_DIM   4096
#define H1      1024
#define DIN     (L_DIM * 19)        // 77824
#define NCHUNK1 512                 // 152 rows each  (512*152 = 77824); 2 blocks/CU balanced
#define ROWS1   152
#define NCHUNK2 256                 // 4 rows each    (256*4 = 1024); 1 block/CU
#define ROWS2   4

// ---------------------------------------------------------------------------
// y[row] = dot(A[row,:], x)   — block-per-row, float4, LDS tree reduce
// ---------------------------------------------------------------------------
__global__ void gemv_rows(const float* __restrict__ A, const float* __restrict__ x,
                          float* __restrict__ y, int C4 /* cols/4 */) {
    const int tid = threadIdx.x;
    const int row = blockIdx.x;
    const float4* A4 = (const float4*)A + (size_t)row * C4;
    const float4* X4 = (const float4*)x;
    float acc = 0.f;
    #pragma unroll 4
    for (int p = tid; p < C4; p += 256) {
        float4 a = A4[p];
        float4 b = X4[p];
        acc += a.x * b.x + a.y * b.y + a.z * b.z + a.w * b.w;
    }
    __shared__ float s[256];
    s[tid] = acc;
    __syncthreads();
    for (int off = 128; off > 0; off >>= 1) {
        if (tid < off) s[tid] += s[tid + off];
        __syncthreads();
    }
    if (tid == 0) y[row] = s[0];
}

// ---------------------------------------------------------------------------
// T-GEMV + fused P1 build:
//   tze = dot(T[row,:], Ze);  P1(row,c) = X[row]*W1[0][c] + tze*W1[1][c]
// P1 stored as [k4][c][4] tile: P[(k>>2)*64 + c*4 + (k&3)]
// ---------------------------------------------------------------------------
__global__ void gemv_T_p1(const float* __restrict__ T, const float* __restrict__ Ze,
                          const float* __restrict__ X, const float* __restrict__ W1,
                          float* __restrict__ P1) {
    const int tid = threadIdx.x;
    const int row = blockIdx.x;
    const float4* A4 = (const float4*)T + (size_t)row * (N_EDGES / 4);
    const float4* X4 = (const float4*)Ze;
    float acc = 0.f;
    #pragma unroll 4
    for (int p = tid; p < N_EDGES / 4; p += 256) {
        float4 a = A4[p];
        float4 b = X4[p];
        acc += a.x * b.x + a.y * b.y + a.z * b.z + a.w * b.w;
    }
    __shared__ float s[256];
    s[tid] = acc;
    __syncthreads();
    for (int off = 128; off > 0; off >>= 1) {
        if (tid < off) s[tid] += s[tid + off];
        __syncthreads();
    }
    if (tid < 16) {
        const float tze = s[0];
        P1[(row >> 2) * 64 + tid * 4 + (row & 3)] = X[row] * W1[tid] + tze * W1[16 + tid];
    }
}

// ---------------------------------------------------------------------------
// Out = adj_v @ P (+bias, opt relu)  — LDS-staged, latency-optimized.
// 256 blocks x 8 rows. Stage 8 adj_v rows (64KB) into LDS with coalesced
// float4 loads, then thread=(row, p=k-slice) keeps 16 c-accumulators in
// registers; shfl_xor reduce over the 32 p lanes (half-wave = one row).
// P ([512][16][4] tile) is ~L1/L2-resident (8KB working set per it-step).
// fuse_p2: Hh = relu(acc+bias) stays in LDS; P2(k,c2) = sum_h Hh[k][h]*W2[h][c2]
//          written as tile. Else: out row-major [2048][16] with +bias.
// ---------------------------------------------------------------------------
__global__ __launch_bounds__(256) void adjmul_lds(
        const float* __restrict__ A, const float* __restrict__ P,
        const float* __restrict__ bias, const float* __restrict__ W2,
        float* __restrict__ outp, int fuse_p2) {
    __shared__ float As[8][2052];    // +4 pad: row stride shifts banks by 4
    __shared__ float hs[8][16];
    const int tid = threadIdx.x;
    const int row0 = blockIdx.x * 8;
    const float4* Ag = (const float4*)A;
    #pragma unroll
    for (int r = 0; r < 8; ++r) {
        float4 v0 = Ag[(size_t)(row0 + r) * 512 + tid];
        float4 v1 = Ag[(size_t)(row0 + r) * 512 + 256 + tid];
        *(float4*)&As[r][tid * 4] = v0;
        *(float4*)&As[r][1024 + tid * 4] = v1;
    }
    __syncthreads();

    const int row = tid >> 5, p = tid & 31;
    const float4* P4 = (const float4*)P;
    float acc[16];
    #pragma unroll
    for (int c = 0; c < 16; ++c) acc[c] = 0.f;
    #pragma unroll 2
    for (int it = 0; it < 16; ++it) {
        const int k4 = it * 32 + p;              // interleaved k-slices
        float4 a = *(const float4*)&As[row][k4 * 4];
        const float4* Pr = P4 + (size_t)k4 * 16;
        #pragma unroll
        for (int c = 0; c < 16; ++c) {
            float4 pv = Pr[c];
            acc[c] += a.x * pv.x + a.y * pv.y + a.z * pv.z + a.w * pv.w;
        }
    }
    #pragma unroll
    for (int c = 0; c < 16; ++c) {
        float v = acc[c];
        v += __shfl_xor(v, 1);  v += __shfl_xor(v, 2);  v += __shfl_xor(v, 4);
        v += __shfl_xor(v, 8);  v += __shfl_xor(v, 16);
        acc[c] = v;
    }

    if (fuse_p2) {
        if (p == 0) {
            #pragma unroll
            for (int c = 0; c < 16; ++c) hs[row][c] = fmaxf(acc[c] + bias[c], 0.f);
        }
        __syncthreads();
        if (tid < 128) {
            const int k = tid >> 4, c2 = tid & 15;
            float sv = 0.f;
            #pragma unroll
            for (int h = 0; h < 16; ++h) sv += hs[k][h] * W2[h * 16 + c2];
            const int kg = row0 + k;
            outp[(kg >> 2) * 64 + c2 * 4 + (kg & 3)] = sv;
        }
    } else {
        if (p == 0) {
            const int grow = row0 + row;
            #pragma unroll
            for (int c = 0; c < 16; ++c) outp[grow * 16 + c] = acc[c] + bias[c];
        }
    }
}

// ---------------------------------------------------------------------------
// Fused single-block prep:
//   src[i] = clamp(inclusive_cumsum(flag)[i]-1, 0, N_NODES-1)  (i < L)
//   lse[0] = max(cost) + log(sum(exp(cost-max)))
// Parallel Hillis-Steele scan (the old thread-0 serial 256-iter loop was
// ~4us of pure critical-path serialization). float4 loads throughout.
// ---------------------------------------------------------------------------
__global__ void prep_kernel(const float* __restrict__ flag, const float* __restrict__ cost,
                            int* __restrict__ src, float* __restrict__ lse) {
    __shared__ int   si[256];
    __shared__ float sf[256];
    const int tid = threadIdx.x;

    // --- load 16 flags via 4x float4, build local count ---
    const int base = tid * 16;
    const float4* F4 = (const float4*)flag;
    float fv[16];
    #pragma unroll
    for (int q = 0; q < 4; ++q) {
        float4 v = F4[tid * 4 + q];
        fv[q * 4 + 0] = v.x; fv[q * 4 + 1] = v.y; fv[q * 4 + 2] = v.z; fv[q * 4 + 3] = v.w;
    }
    int f[16];
    int local = 0;
    #pragma unroll
    for (int e = 0; e < 16; ++e) {
        f[e] = fv[e] > 0.5f ? 1 : 0;
        local += f[e];
    }
    si[tid] = local;
    __syncthreads();

    // --- Hillis-Steele inclusive scan over 256 per-thread counts ---
    #pragma unroll
    for (int off = 1; off < 256; off <<= 1) {
        int t = si[tid];
        if (tid >= off) t += si[tid - off];
        __syncthreads();
        si[tid] = t;
        __syncthreads();
    }
    int run = si[tid] - local;       // exclusive prefix for this thread's chunk
    #pragma unroll
    for (int e = 0; e < 16; ++e) {
        run += f[e];
        int v = run - 1;
        v = v < 0 ? 0 : (v > N_NODES - 1 ? N_NODES - 1 : v);
        src[base + e] = v;
    }

    // --- logsumexp over cost (float4 loads; 4 elems/thread) ---
    const float4* C4v = (const float4*)cost;
    float4 cv = C4v[tid * 4 + 0];
    float4 cw = C4v[tid * 4 + 1];
    float4 cy = C4v[tid * 4 + 2];
    float4 cz = C4v[tid * 4 + 3];
    float m = fmaxf(fmaxf(fmaxf(cv.x, cv.y), fmaxf(cv.z, cv.w)),
                    fmaxf(fmaxf(cw.x, cw.y), fmaxf(cw.z, cw.w)));
    m = fmaxf(m, fmaxf(fmaxf(fmaxf(cy.x, cy.y), fmaxf(cy.z, cy.w)),
                       fmaxf(fmaxf(cz.x, cz.y), fmaxf(cz.z, cz.w))));
    sf[tid] = m;
    __syncthreads();
    for (int off = 128; off > 0; off >>= 1) {
        if (tid < off) sf[tid] = fmaxf(sf[tid], sf[tid + off]);
        __syncthreads();
    }
    const float M = sf[0];
    __syncthreads();
    float sum = expf(cv.x - M) + expf(cv.y - M) + expf(cv.z - M) + expf(cv.w - M)
              + expf(cw.x - M) + expf(cw.y - M) + expf(cw.z - M) + expf(cw.w - M)
              + expf(cy.x - M) + expf(cy.y - M) + expf(cy.z - M) + expf(cy.w - M)
              + expf(cz.x - M) + expf(cz.y - M) + expf(cz.z - M) + expf(cz.w - M);
    sf[tid] = sum;
    __syncthreads();
    for (int off = 128; off > 0; off >>= 1) {
        if (tid < off) sf[tid] += sf[tid + off];
        __syncthreads();
    }
    if (tid == 0) lse[0] = M + logf(sf[0]);
}

// ---------------------------------------------------------------------------
// Fused obs-build + Wm1 split-K GEMV.
// Block b covers DIN rows [b*152, b*152+152). Thread r<152 computes obs value
// r on the fly; ballot-compaction keeps only nonzeros (exact: 0*finite==0,
// skips ~45% of Wm1 rows); inner loop is branch-free, thread t owns W columns
// 4t..4t+3 (float4, 1KB contiguous per wave per row).
// ---------------------------------------------------------------------------
__global__ void gemv_obs_wm1(const float* __restrict__ W, const float* __restrict__ cost,
                             const float* __restrict__ flag, const float* __restrict__ dual,
                             const float* __restrict__ emb, const int* __restrict__ src,
                             const float* __restrict__ lse, float* __restrict__ partial) {
    const int tid = threadIdx.x;                     // 256
    const int row0 = blockIdx.x * ROWS1;
    __shared__ float xs[256];
    __shared__ float xv_c[256];
    __shared__ int   ri_c[256];
    __shared__ int   wcnt[4];
    __shared__ int   wbase[4];
    __shared__ int   cnt_s;
    if (tid < ROWS1) {
        const int i_din = row0 + tid;
        const int i = i_din / 19;
        const int c = i_din - i * 19;
        const float fl = flag[i];
        float v;
        if (c == 0)      v = cost[i] - lse[0];
        else if (c == 1) v = fl;
        else if (c == 2) v = (fl > 0.5f) ? dual[src[i]] : 1.0f;
        else             v = (fl > 0.5f) ? emb[src[i] * 16 + (c - 3)] : 0.0f;
        xs[tid] = v;
    }
    __syncthreads();

    const bool pred = (tid < ROWS1) && (xs[tid] != 0.0f);
    const unsigned long long mask = __ballot(pred);
    const int lane = tid & 63, wid = tid >> 6;
    const int wpre = __popcll(mask & ((1ull << lane) - 1ull));
    if (lane == 0) wcnt[wid] = __popcll(mask);
    __syncthreads();
    if (tid == 0) {
        int r = 0;
        #pragma unroll
        for (int w = 0; w < 4; ++w) { wbase[w] = r; r += wcnt[w]; }
        cnt_s = r;
    }
    __syncthreads();
    if (pred) {
        const int idx = wbase[wid] + wpre;
        xv_c[idx] = xs[tid];
        ri_c[idx] = tid;
    }
    __syncthreads();

    const int cnt = cnt_s;
    const float4* W4 = (const float4*)W;
    float4 acc = {0.f, 0.f, 0.f, 0.f};
    #pragma unroll 4
    for (int ii = 0; ii < cnt; ++ii) {
        const float xv = xv_c[ii];
        float4 w = W4[(size_t)(row0 + ri_c[ii]) * 256 + tid];
        acc.x += xv * w.x; acc.y += xv * w.y; acc.z += xv * w.z; acc.w += xv * w.w;
    }
    ((float4*)partial)[(size_t)blockIdx.x * 256 + tid] = acc;
}

// ---------------------------------------------------------------------------
// Fused h1-reduce + Wm2 split-K GEMV.
// Block b: (1) h[i] = tanh(sum_k part1[k][4b+i] + bm1[4b+i]) for i=0..3,
//          reduced cooperatively; (2) part2[b][t] = sum_i h[i]*Wm2[4b+i][4t..].
// 256 blocks = 1/CU, balanced.
// ---------------------------------------------------------------------------
__global__ void wm2_fused(const float* __restrict__ part1, const float* __restrict__ bm1,
                          const float* __restrict__ Wm2, float* __restrict__ part2) {
    const int tid = threadIdx.x;                     // 256
    const int j0 = blockIdx.x * ROWS2;               // 4 input rows per block
    const int jj = tid & 3, kg = tid >> 2;           // 64 k-groups x 4 cols
    float sum = 0.f;
    for (int k = kg; k < NCHUNK1; k += 64) sum += part1[(size_t)k * 1024 + j0 + jj];
    __shared__ float s[256];
    __shared__ float hsv[4];
    s[tid] = sum;
    __syncthreads();
    for (int off = 32; off > 0; off >>= 1) {
        if (kg < off) s[tid] += s[tid + off * 4];
        __syncthreads();
    }
    if (tid < 4) hsv[tid] = tanhf(s[tid] + bm1[j0 + tid]);
    __syncthreads();

    const float4* W4 = (const float4*)Wm2;
    float4 acc = {0.f, 0.f, 0.f, 0.f};
    #pragma unroll
    for (int i = 0; i < ROWS2; ++i) {
        const float xv = hsv[i];
        float4 w = W4[(size_t)(j0 + i) * 256 + tid];
        acc.x += xv * w.x; acc.y += xv * w.y; acc.z += xv * w.z; acc.w += xv * w.w;
    }
    ((float4*)part2)[(size_t)blockIdx.x * 256 + tid] = acc;
}

// ---------------------------------------------------------------------------
// out[j] = act( sum_k partial[k][j] + bias[j] )
// grid: 16 blocks x 64 j; 256 thr = 4 kg x 64 j -> fully coalesced reads.
// ---------------------------------------------------------------------------
__global__ void reduce_cols(const float* __restrict__ partial, int nchunk,
                            const float* __restrict__ bias, float* __restrict__ out,
                            int do_tanh) {
    const int tid = threadIdx.x;                     // 256 = 4 kg x 64 j
    const int jj = tid & 63, kg = tid >> 6;
    const int j = blockIdx.x * 64 + jj;
    float sum = 0.f;
    for (int k = kg; k < nchunk; k += 4) sum += partial[(size_t)k * 1024 + j];
    __shared__ float s[256];
    s[tid] = sum;
    __syncthreads();
    if (kg < 2) s[tid] += s[tid + 128];
    __syncthreads();
    if (kg == 0) {
        float v = s[tid] + s[tid + 64] + bias[j];
        out[j] = do_tanh ? tanhf(v) : v;
    }
}

// ---------------------------------------------------------------------------
// out[0] = dot(h, w) + b[0]   — one block, 1024 elements (8 KB read)
// ---------------------------------------------------------------------------
__global__ void final_dot(const float* __restrict__ h, const float* __restrict__ w,
                          const float* __restrict__ b, float* __restrict__ out) {
    const int tid = threadIdx.x;                     // 256
    float4 a  = ((const float4*)h)[tid];
    float4 ww = ((const float4*)w)[tid];
    float acc = a.x * ww.x + a.y * ww.y + a.z * ww.z + a.w * ww.w;
    __shared__ float s[256];
    s[tid] = acc;
    __syncthreads();
    for (int off = 128; off > 0; off >>= 1) {
        if (tid < off) s[tid] += s[tid + off];
        __syncthreads();
    }
    if (tid == 0) out[0] = s[0] + b[0];
}

// ---------------------------------------------------------------------------
extern "C" void kernel_launch(void* const* d_in, const int* in_sizes, int n_in,
                              void* d_out, int out_size, void* d_ws, size_t ws_size,
                              hipStream_t stream) {
    const float* X      = (const float*)d_in[0];   // [2048,1]
    const float* Z      = (const float*)d_in[1];   // [4096,1]
    const float* adj_e  = (const float*)d_in[2];   // [4096,4096]
    const float* adj_v  = (const float*)d_in[3];   // [2048,2048]
    const float* T      = (const float*)d_in[4];   // [2048,4096]
    const float* cost   = (const float*)d_in[5];   // [4096]
    const float* flag   = (const float*)d_in[6];   // [4096]
    const float* dual   = (const float*)d_in[7];   // [2048,1]
    const float* W1     = (const float*)d_in[8];   // [2,16]
    const float* b1     = (const float*)d_in[9];   // [16]
    const float* W2     = (const float*)d_in[10];  // [16,16]
    const float* b2     = (const float*)d_in[11];  // [16]
    const float* Wm1    = (const float*)d_in[12];  // [77824,1024]
    const float* bm1    = (const float*)d_in[13];  // [1024]
    const float* Wm2    = (const float*)d_in[14];  // [1024,1024]
    const float* bm2    = (const float*)d_in[15];  // [1024]
    const float* Wm3    = (const float*)d_in[16];  // [1024,1]
    const float* bm3    = (const float*)d_in[17];  // [1]
    float* out = (float*)d_out;

    // workspace carve-up (256B aligned, gap-free; total ~3.58 MB).
    // NOTE round-5 layout had h2 OVERLAPPING part2's tail (alias race) — fixed.
    char* ws = (char*)d_ws;
    float* Ze    = (float*)(ws + 0);          //  16 KB  [4096]          ends   16384
    float* P1    = (float*)(ws + 16384);      // 128 KB  tile            ends  147456
    float* P2    = (float*)(ws + 147456);     // 128 KB  tile            ends  278528
    float* emb   = (float*)(ws + 278528);     // 128 KB  [2048][16]      ends  409600
    int*   src   = (int*)  (ws + 409600);     //  16 KB  [4096]          ends  425984
    float* lse   = (float*)(ws + 425984);     //  256 B                  ends  426240
    float* part1 = (float*)(ws + 426240);     //   2 MB  [512][1024]     ends 2523392
    float* part2 = (float*)(ws + 2523392);    //   1 MB  [256][1024]     ends 3571968
    float* h2    = (float*)(ws + 3571968);    //   4 KB  [1024]          ends 3576064

    // --- obs prep (no GCN dependency; issue first) ---
    prep_kernel<<<1, 256, 0, stream>>>(flag, cost, src, lse);                 // scan + logsumexp

    // --- GCN (4 nodes) ---
    gemv_rows<<<N_EDGES, 256, 0, stream>>>(adj_e, Z, Ze, N_EDGES / 4);        // Ze = adj_e @ Z
    gemv_T_p1<<<N_NODES, 256, 0, stream>>>(T, Ze, X, W1, P1);                 // TZe + P1 build
    adjmul_lds<<<N_NODES / 8, 256, 0, stream>>>(adj_v, P1, b1, W2, P2, 1);    // Hh=relu(..+b1); P2=Hh@W2
    adjmul_lds<<<N_NODES / 8, 256, 0, stream>>>(adj_v, P2, b2, W2, emb, 0);   // emb = adj_v@P2 + b2

    // --- MLP (4 nodes) ---
    gemv_obs_wm1<<<NCHUNK1, 256, 0, stream>>>(Wm1, cost, flag, dual, emb,
                                              src, lse, part1);               // obs (on the fly) @ Wm1
    wm2_fused<<<NCHUNK2, 256, 0, stream>>>(part1, bm1, Wm2, part2);           // h1 = tanh(.); h1 @ Wm2
    reduce_cols<<<16, 256, 0, stream>>>(part2, NCHUNK2, bm2, h2, 1);          // +bm2, tanh
    final_dot<<<1, 256, 0, stream>>>(h2, Wm3, bm3, out);                      // h2 @ Wm3 + bm3
}

// Round 8
// 568.237 us; speedup vs baseline: 1.0360x; 1.0360x over previous
//
#include <hip/hip_runtime.h>
#include <math.h>

// ---------------------------------------------------------------------------
// Sizes (fixed by the reference)
// ---------------------------------------------------------------------------
#define N_NODES 2048
#define N_EDGES 4096
#define L_DIM   4096
#define H1      1024
#define DIN     (L_DIM * 19)        // 77824
#define NCHUNK1 1024                // 76 rows each (1024*76 = 77824); 4 blocks/CU
#define ROWS1   76
#define NCHUNK2 256                 // 4 rows each  (256*4 = 1024); 1 block/CU
#define ROWS2   4

// nontemporal float4 load (evict-first in L2 — for stream-once matrices)
typedef float v4f __attribute__((ext_vector_type(4)));
__device__ __forceinline__ float4 ntload4(const float4* p) {
    v4f v = __builtin_nontemporal_load((const v4f*)p);
    float4 r; r.x = v.x; r.y = v.y; r.z = v.z; r.w = v.w;
    return r;
}

// ---------------------------------------------------------------------------
// y[row] = dot(A[row,:], x) — block-per-row, nt float4 A-loads,
// shuffle reduce (6 xor steps) + 1 barrier for cross-wave combine.
// ---------------------------------------------------------------------------
__global__ void gemv_rows(const float* __restrict__ A, const float* __restrict__ x,
                          float* __restrict__ y, int C4 /* cols/4 */) {
    const int tid = threadIdx.x;
    const int row = blockIdx.x;
    const float4* A4 = (const float4*)A + (size_t)row * C4;
    const float4* X4 = (const float4*)x;
    float acc = 0.f;
    #pragma unroll 4
    for (int p = tid; p < C4; p += 256) {
        float4 a = ntload4(A4 + p);
        float4 b = X4[p];
        acc += a.x * b.x + a.y * b.y + a.z * b.z + a.w * b.w;
    }
    acc += __shfl_xor(acc, 1);  acc += __shfl_xor(acc, 2);  acc += __shfl_xor(acc, 4);
    acc += __shfl_xor(acc, 8);  acc += __shfl_xor(acc, 16); acc += __shfl_xor(acc, 32);
    __shared__ float s[4];
    if ((tid & 63) == 0) s[tid >> 6] = acc;
    __syncthreads();
    if (tid == 0) y[row] = s[0] + s[1] + s[2] + s[3];
}

// ---------------------------------------------------------------------------
// T-GEMV + fused P1 build:
//   tze = dot(T[row,:], Ze);  P1(row,c) = X[row]*W1[0][c] + tze*W1[1][c]
// P1 stored as [k4][c][4] tile: P[(k>>2)*64 + c*4 + (k&3)]
// ---------------------------------------------------------------------------
__global__ void gemv_T_p1(const float* __restrict__ T, const float* __restrict__ Ze,
                          const float* __restrict__ X, const float* __restrict__ W1,
                          float* __restrict__ P1) {
    const int tid = threadIdx.x;
    const int row = blockIdx.x;
    const float4* A4 = (const float4*)T + (size_t)row * (N_EDGES / 4);
    const float4* X4 = (const float4*)Ze;
    float acc = 0.f;
    #pragma unroll 4
    for (int p = tid; p < N_EDGES / 4; p += 256) {
        float4 a = ntload4(A4 + p);
        float4 b = X4[p];
        acc += a.x * b.x + a.y * b.y + a.z * b.z + a.w * b.w;
    }
    acc += __shfl_xor(acc, 1);  acc += __shfl_xor(acc, 2);  acc += __shfl_xor(acc, 4);
    acc += __shfl_xor(acc, 8);  acc += __shfl_xor(acc, 16); acc += __shfl_xor(acc, 32);
    __shared__ float s[4];
    if ((tid & 63) == 0) s[tid >> 6] = acc;
    __syncthreads();
    if (tid < 16) {
        const float tze = s[0] + s[1] + s[2] + s[3];
        P1[(row >> 2) * 64 + tid * 4 + (row & 3)] = X[row] * W1[tid] + tze * W1[16 + tid];
    }
}

// ---------------------------------------------------------------------------
// Out = adj_v @ P (+bias, opt relu)  — LDS-staged, latency-optimized.
// 256 blocks x 8 rows. Stage 8 adj_v rows (64KB) into LDS (nt, coalesced),
// then thread=(row, p=k-slice) keeps 16 c-accumulators; shfl_xor reduce over
// the 32 p lanes. P ([512][16][4] tile) is L1/L2-resident.
// fuse_p2: Hh = relu(acc+bias) in LDS; P2(k,c2) = sum_h Hh[k][h]*W2[h][c2].
// ---------------------------------------------------------------------------
__global__ __launch_bounds__(256) void adjmul_lds(
        const float* __restrict__ A, const float* __restrict__ P,
        const float* __restrict__ bias, const float* __restrict__ W2,
        float* __restrict__ outp, int fuse_p2) {
    __shared__ float As[8][2052];    // +4 pad: row stride shifts banks by 4
    __shared__ float hs[8][16];
    const int tid = threadIdx.x;
    const int row0 = blockIdx.x * 8;
    const float4* Ag = (const float4*)A;
    #pragma unroll
    for (int r = 0; r < 8; ++r) {
        float4 v0 = ntload4(Ag + (size_t)(row0 + r) * 512 + tid);
        float4 v1 = ntload4(Ag + (size_t)(row0 + r) * 512 + 256 + tid);
        *(float4*)&As[r][tid * 4] = v0;
        *(float4*)&As[r][1024 + tid * 4] = v1;
    }
    __syncthreads();

    const int row = tid >> 5, p = tid & 31;
    const float4* P4 = (const float4*)P;
    float acc[16];
    #pragma unroll
    for (int c = 0; c < 16; ++c) acc[c] = 0.f;
    #pragma unroll 2
    for (int it = 0; it < 16; ++it) {
        const int k4 = it * 32 + p;              // interleaved k-slices
        float4 a = *(const float4*)&As[row][k4 * 4];
        const float4* Pr = P4 + (size_t)k4 * 16;
        #pragma unroll
        for (int c = 0; c < 16; ++c) {
            float4 pv = Pr[c];
            acc[c] += a.x * pv.x + a.y * pv.y + a.z * pv.z + a.w * pv.w;
        }
    }
    #pragma unroll
    for (int c = 0; c < 16; ++c) {
        float v = acc[c];
        v += __shfl_xor(v, 1);  v += __shfl_xor(v, 2);  v += __shfl_xor(v, 4);
        v += __shfl_xor(v, 8);  v += __shfl_xor(v, 16);
        acc[c] = v;
    }

    if (fuse_p2) {
        if (p == 0) {
            #pragma unroll
            for (int c = 0; c < 16; ++c) hs[row][c] = fmaxf(acc[c] + bias[c], 0.f);
        }
        __syncthreads();
        if (tid < 128) {
            const int k = tid >> 4, c2 = tid & 15;
            float sv = 0.f;
            #pragma unroll
            for (int h = 0; h < 16; ++h) sv += hs[k][h] * W2[h * 16 + c2];
            const int kg = row0 + k;
            outp[(kg >> 2) * 64 + c2 * 4 + (kg & 3)] = sv;
        }
    } else {
        if (p == 0) {
            const int grow = row0 + row;
            #pragma unroll
            for (int c = 0; c < 16; ++c) outp[grow * 16 + c] = acc[c] + bias[c];
        }
    }
}

// ---------------------------------------------------------------------------
// Fused single-block prep: parallel scan (src) + logsumexp (lse)
// ---------------------------------------------------------------------------
__global__ void prep_kernel(const float* __restrict__ flag, const float* __restrict__ cost,
                            int* __restrict__ src, float* __restrict__ lse) {
    __shared__ int   si[256];
    __shared__ float sf[256];
    const int tid = threadIdx.x;

    const int base = tid * 16;
    const float4* F4 = (const float4*)flag;
    float fv[16];
    #pragma unroll
    for (int q = 0; q < 4; ++q) {
        float4 v = F4[tid * 4 + q];
        fv[q * 4 + 0] = v.x; fv[q * 4 + 1] = v.y; fv[q * 4 + 2] = v.z; fv[q * 4 + 3] = v.w;
    }
    int f[16];
    int local = 0;
    #pragma unroll
    for (int e = 0; e < 16; ++e) {
        f[e] = fv[e] > 0.5f ? 1 : 0;
        local += f[e];
    }
    si[tid] = local;
    __syncthreads();
    #pragma unroll
    for (int off = 1; off < 256; off <<= 1) {
        int t = si[tid];
        if (tid >= off) t += si[tid - off];
        __syncthreads();
        si[tid] = t;
        __syncthreads();
    }
    int run = si[tid] - local;       // exclusive prefix
    #pragma unroll
    for (int e = 0; e < 16; ++e) {
        run += f[e];
        int v = run - 1;
        v = v < 0 ? 0 : (v > N_NODES - 1 ? N_NODES - 1 : v);
        src[base + e] = v;
    }

    const float4* C4v = (const float4*)cost;
    float4 cv = C4v[tid * 4 + 0];
    float4 cw = C4v[tid * 4 + 1];
    float4 cy = C4v[tid * 4 + 2];
    float4 cz = C4v[tid * 4 + 3];
    float m = fmaxf(fmaxf(fmaxf(cv.x, cv.y), fmaxf(cv.z, cv.w)),
                    fmaxf(fmaxf(cw.x, cw.y), fmaxf(cw.z, cw.w)));
    m = fmaxf(m, fmaxf(fmaxf(fmaxf(cy.x, cy.y), fmaxf(cy.z, cy.w)),
                       fmaxf(fmaxf(cz.x, cz.y), fmaxf(cz.z, cz.w))));
    sf[tid] = m;
    __syncthreads();
    for (int off = 128; off > 0; off >>= 1) {
        if (tid < off) sf[tid] = fmaxf(sf[tid], sf[tid + off]);
        __syncthreads();
    }
    const float M = sf[0];
    __syncthreads();
    float sum = expf(cv.x - M) + expf(cv.y - M) + expf(cv.z - M) + expf(cv.w - M)
              + expf(cw.x - M) + expf(cw.y - M) + expf(cw.z - M) + expf(cw.w - M)
              + expf(cy.x - M) + expf(cy.y - M) + expf(cy.z - M) + expf(cy.w - M)
              + expf(cz.x - M) + expf(cz.y - M) + expf(cz.z - M) + expf(cz.w - M);
    sf[tid] = sum;
    __syncthreads();
    for (int off = 128; off > 0; off >>= 1) {
        if (tid < off) sf[tid] += sf[tid + off];
        __syncthreads();
    }
    if (tid == 0) lse[0] = M + logf(sf[0]);
}

// ---------------------------------------------------------------------------
// Fused obs-build + Wm1 split-K GEMV.
// 1024 blocks x 76 rows (4 blocks/CU -> 16 waves/CU of MLP). Thread r<76
// computes obs value r on the fly; ballot-compaction keeps only nonzeros
// (exact: 0*finite==0, skips ~45% of Wm1 rows); inner loop branch-free;
// thread t owns W cols 4t..4t+3 (nt float4, 1KB contiguous per wave per row).
// ---------------------------------------------------------------------------
__global__ void gemv_obs_wm1(const float* __restrict__ W, const float* __restrict__ cost,
                             const float* __restrict__ flag, const float* __restrict__ dual,
                             const float* __restrict__ emb, const int* __restrict__ src,
                             const float* __restrict__ lse, float* __restrict__ partial) {
    const int tid = threadIdx.x;                     // 256
    const int row0 = blockIdx.x * ROWS1;
    __shared__ float xs[128];
    __shared__ float xv_c[128];
    __shared__ int   ri_c[128];
    __shared__ int   wcnt[2];
    __shared__ int   cnt_s;
    if (tid < ROWS1) {
        const int i_din = row0 + tid;
        const int i = i_din / 19;
        const int c = i_din - i * 19;
        const float fl = flag[i];
        float v;
        if (c == 0)      v = cost[i] - lse[0];
        else if (c == 1) v = fl;
        else if (c == 2) v = (fl > 0.5f) ? dual[src[i]] : 1.0f;
        else             v = (fl > 0.5f) ? emb[src[i] * 16 + (c - 3)] : 0.0f;
        xs[tid] = v;
    }
    __syncthreads();

    // stable wave-parallel compaction (rows live in waves 0..1 since ROWS1<=128)
    const bool pred = (tid < ROWS1) && (xs[tid] != 0.0f);
    const unsigned long long mask = __ballot(pred);
    const int lane = tid & 63, wid = tid >> 6;
    const int wpre = __popcll(mask & ((1ull << lane) - 1ull));
    if (lane == 0 && wid < 2) wcnt[wid] = __popcll(mask);
    __syncthreads();
    if (tid == 0) cnt_s = wcnt[0] + wcnt[1];
    __syncthreads();
    if (pred) {
        const int idx = (wid == 0 ? 0 : wcnt[0]) + wpre;
        xv_c[idx] = xs[tid];
        ri_c[idx] = tid;
    }
    __syncthreads();

    const int cnt = cnt_s;
    const float4* W4 = (const float4*)W;
    float4 acc = {0.f, 0.f, 0.f, 0.f};
    #pragma unroll 4
    for (int ii = 0; ii < cnt; ++ii) {
        const float xv = xv_c[ii];
        float4 w = ntload4(W4 + (size_t)(row0 + ri_c[ii]) * 256 + tid);
        acc.x += xv * w.x; acc.y += xv * w.y; acc.z += xv * w.z; acc.w += xv * w.w;
    }
    ((float4*)partial)[(size_t)blockIdx.x * 256 + tid] = acc;
}

// ---------------------------------------------------------------------------
// Fused h1-reduce + Wm2 split-K GEMV.
// Block b: (1) h[i] = tanh(sum_k part1[k][4b+i] + bm1[4b+i]) for i=0..3;
//          (2) part2[b][t] = sum_i h[i]*Wm2[4b+i][4t..4t+3].
// ---------------------------------------------------------------------------
__global__ void wm2_fused(const float* __restrict__ part1, const float* __restrict__ bm1,
                          const float* __restrict__ Wm2, float* __restrict__ part2) {
    const int tid = threadIdx.x;                     // 256
    const int j0 = blockIdx.x * ROWS2;               // 4 input rows per block
    const int jj = tid & 3, kg = tid >> 2;           // 64 k-groups x 4 cols
    float sum = 0.f;
    for (int k = kg; k < NCHUNK1; k += 64) sum += part1[(size_t)k * 1024 + j0 + jj];
    __shared__ float s[256];
    __shared__ float hsv[4];
    s[tid] = sum;
    __syncthreads();
    for (int off = 32; off > 0; off >>= 1) {
        if (kg < off) s[tid] += s[tid + off * 4];
        __syncthreads();
    }
    if (tid < 4) hsv[tid] = tanhf(s[tid] + bm1[j0 + tid]);
    __syncthreads();

    const float4* W4 = (const float4*)Wm2;
    float4 acc = {0.f, 0.f, 0.f, 0.f};
    #pragma unroll
    for (int i = 0; i < ROWS2; ++i) {
        const float xv = hsv[i];
        float4 w = ntload4(W4 + (size_t)(j0 + i) * 256 + tid);
        acc.x += xv * w.x; acc.y += xv * w.y; acc.z += xv * w.z; acc.w += xv * w.w;
    }
    ((float4*)part2)[(size_t)blockIdx.x * 256 + tid] = acc;
}

// ---------------------------------------------------------------------------
// out[j] = act( sum_k partial[k][j] + bias[j] )
// grid: 16 blocks x 64 j; 256 thr = 4 kg x 64 j -> fully coalesced reads.
// ---------------------------------------------------------------------------
__global__ void reduce_cols(const float* __restrict__ partial, int nchunk,
                            const float* __restrict__ bias, float* __restrict__ out,
                            int do_tanh) {
    const int tid = threadIdx.x;                     // 256 = 4 kg x 64 j
    const int jj = tid & 63, kg = tid >> 6;
    const int j = blockIdx.x * 64 + jj;
    float sum = 0.f;
    for (int k = kg; k < nchunk; k += 4) sum += partial[(size_t)k * 1024 + j];
    __shared__ float s[256];
    s[tid] = sum;
    __syncthreads();
    if (kg < 2) s[tid] += s[tid + 128];
    __syncthreads();
    if (kg == 0) {
        float v = s[tid] + s[tid + 64] + bias[j];
        out[j] = do_tanh ? tanhf(v) : v;
    }
}

// ---------------------------------------------------------------------------
// out[0] = dot(h, w) + b[0]   — one block, 1024 elements (8 KB read)
// ---------------------------------------------------------------------------
__global__ void final_dot(const float* __restrict__ h, const float* __restrict__ w,
                          const float* __restrict__ b, float* __restrict__ out) {
    const int tid = threadIdx.x;                     // 256
    float4 a  = ((const float4*)h)[tid];
    float4 ww = ((const float4*)w)[tid];
    float acc = a.x * ww.x + a.y * ww.y + a.z * ww.z + a.w * ww.w;
    __shared__ float s[256];
    s[tid] = acc;
    __syncthreads();
    for (int off = 128; off > 0; off >>= 1) {
        if (tid < off) s[tid] += s[tid + off];
        __syncthreads();
    }
    if (tid == 0) out[0] = s[0] + b[0];
}

// ---------------------------------------------------------------------------
extern "C" void kernel_launch(void* const* d_in, const int* in_sizes, int n_in,
                              void* d_out, int out_size, void* d_ws, size_t ws_size,
                              hipStream_t stream) {
    const float* X      = (const float*)d_in[0];   // [2048,1]
    const float* Z      = (const float*)d_in[1];   // [4096,1]
    const float* adj_e  = (const float*)d_in[2];   // [4096,4096]
    const float* adj_v  = (const float*)d_in[3];   // [2048,2048]
    const float* T      = (const float*)d_in[4];   // [2048,4096]
    const float* cost   = (const float*)d_in[5];   // [4096]
    const float* flag   = (const float*)d_in[6];   // [4096]
    const float* dual   = (const float*)d_in[7];   // [2048,1]
    const float* W1     = (const float*)d_in[8];   // [2,16]
    const float* b1     = (const float*)d_in[9];   // [16]
    const float* W2     = (const float*)d_in[10];  // [16,16]
    const float* b2     = (const float*)d_in[11];  // [16]
    const float* Wm1    = (const float*)d_in[12];  // [77824,1024]
    const float* bm1    = (const float*)d_in[13];  // [1024]
    const float* Wm2    = (const float*)d_in[14];  // [1024,1024]
    const float* bm2    = (const float*)d_in[15];  // [1024]
    const float* Wm3    = (const float*)d_in[16];  // [1024,1]
    const float* bm3    = (const float*)d_in[17];  // [1]
    float* out = (float*)d_out;

    // workspace carve-up (256B aligned, gap-free; total ~5.7 MB)
    char* ws = (char*)d_ws;
    float* Ze    = (float*)(ws + 0);          //  16 KB  [4096]          ends   16384
    float* P1    = (float*)(ws + 16384);      // 128 KB  tile            ends  147456
    float* P2    = (float*)(ws + 147456);     // 128 KB  tile            ends  278528
    float* emb   = (float*)(ws + 278528);     // 128 KB  [2048][16]      ends  409600
    int*   src   = (int*)  (ws + 409600);     //  16 KB  [4096]          ends  425984
    float* lse   = (float*)(ws + 425984);     //  256 B                  ends  426240
    float* part1 = (float*)(ws + 426240);     //   4 MB  [1024][1024]    ends 4620544
    float* part2 = (float*)(ws + 4620544);    //   1 MB  [256][1024]     ends 5669120
    float* h2    = (float*)(ws + 5669120);    //   4 KB  [1024]          ends 5673216

    // --- obs prep (no GCN dependency; issue first) ---
    prep_kernel<<<1, 256, 0, stream>>>(flag, cost, src, lse);                 // scan + logsumexp

    // --- GCN (4 nodes) ---
    gemv_rows<<<N_EDGES, 256, 0, stream>>>(adj_e, Z, Ze, N_EDGES / 4);        // Ze = adj_e @ Z
    gemv_T_p1<<<N_NODES, 256, 0, stream>>>(T, Ze, X, W1, P1);                 // TZe + P1 build
    adjmul_lds<<<N_NODES / 8, 256, 0, stream>>>(adj_v, P1, b1, W2, P2, 1);    // Hh=relu(..+b1); P2=Hh@W2
    adjmul_lds<<<N_NODES / 8, 256, 0, stream>>>(adj_v, P2, b2, W2, emb, 0);   // emb = adj_v@P2 + b2

    // --- MLP (4 nodes) ---
    gemv_obs_wm1<<<NCHUNK1, 256, 0, stream>>>(Wm1, cost, flag, dual, emb,
                                              src, lse, part1);               // obs (on the fly) @ Wm1
    wm2_fused<<<NCHUNK2, 256, 0, stream>>>(part1, bm1, Wm2, part2);           // h1 = tanh(.); h1 @ Wm2
    reduce_cols<<<16, 256, 0, stream>>>(part2, NCHUNK2, bm2, h2, 1);          // +bm2, tanh
    final_dot<<<1, 256, 0, stream>>>(h2, Wm3, bm3, out);                      // h2 @ Wm3 + bm3
}